// Round 5
// baseline (136.217 us; speedup 1.0000x reference)
//
#include <hip/hip_runtime.h>
#include <hip/hip_bf16.h>

#define B_   16
#define T_   2500
#define X_   512
#define XT   32
#define SEGS 4
#define SEGR 640
#define NSX  (X_ / XT)            // 16
#define NBLK (B_ * SEGS * NSX)    // 1024

typedef __attribute__((ext_vector_type(4))) float f32x4;
typedef _Float16 h2v __attribute__((ext_vector_type(2)));

__device__ __forceinline__ float dot2f(uint kp, uint vp, float c) {
#if __has_builtin(__builtin_amdgcn_fdot2)
    return __builtin_amdgcn_fdot2(__builtin_bit_cast(h2v, kp),
                                  __builtin_bit_cast(h2v, vp), c, false);
#else
    h2v a = __builtin_bit_cast(h2v, kp), b = __builtin_bit_cast(h2v, vp);
    return fmaf((float)a[0], (float)b[0], fmaf((float)a[1], (float)b[1], c));
#endif
}

// Round-5: round-4's 1-barrier fp8-ring pipeline, with
//  - fp16 product buffer + v_dot2_f32_f16 xconv (halves producer VALU)
//  - DPP 4x4 byte-transpose -> single ds_write_b32 fp8 ring writes
//  - xconv split 3/2 between the two wave-pairs (PB ping-pong for safety)
//  - float4 coalesced staging loads; s_setprio around MFMA cluster.
__global__ __launch_bounds__(256, 3) void coh5(const float* __restrict__ xg,
                                               const float* __restrict__ yg,
                                               float* __restrict__ partial)
{
    __shared__ float ktn[104];
    __shared__ float kxn[12];
    __shared__ float norm2[2];
    __shared__ unsigned long long XS[18][5][34];  // fp8 ring: byte rs of [slot][f][col] = rowslot
    __shared__ ushort PB[2][5][16][66];           // fp16 products, ping-pong; col p <-> x0-18+p
    __shared__ float wred[4];

    const int tid  = threadIdx.x;
    const int lane = tid & 63;
    const int w    = tid >> 6;
    const int g    = lane >> 4;
    const int ln16 = lane & 15;
    const int pair = w >> 1;
    const int p01  = w & 1;
    const int prow = lane & 7;      // xconv: row within 8-row group
    const int pcg  = lane >> 3;     // xconv: 4-col group
    const int kq   = lane & 15;     // stage: float4 column
    const int rhal = lane >> 4;     // stage: row within 4-row pass
    const int rr8  = 8 * p01 + prow;

    // DPP quad-transpose constants (4x4 bytes across lanes 4a..4a+3)
    const uint sel1  = (prow & 1) ? 0x07030602u : 0x01050004u;
    const uint sel2  = (prow & 2) ? 0x07060302u : 0x01000504u;
    const int  cidx  = ((prow & 1) << 1) | ((prow >> 1) & 1);
    const int  abyte = (prow & 4);

    const int x0    = blockIdx.x * XT;
    const int seg   = blockIdx.y;
    const int t0    = seg * SEGR;
    const int t_end = min(t0 + SEGR, T_);
    const int nm    = (t_end - t0 + 15) >> 4;
    const int b     = blockIdx.z;

    // ---- normalized Gaussian tables ----
    if (tid < 104) ktn[tid] = 0.0f;
    if (tid < 12)  kxn[tid] = 0.0f;
    __syncthreads();
    if (tid < 101) { float d = (float)(tid - 50); ktn[tid] = expf(-d * d / (2.0f * 21.0f * 21.0f)); }
    if (tid < 11)  { float d = (float)(tid - 5);  kxn[tid] = expf(-d * d / (2.0f * 11.0f * 11.0f)); }
    __syncthreads();
    if (tid == 0) {
        float s = 0.f; for (int i = 0; i < 101; ++i) s += ktn[i]; norm2[0] = 1.0f / s;
        s = 0.f;       for (int i = 0; i < 11;  ++i) s += kxn[i]; norm2[1] = 1.0f / s;
    }
    __syncthreads();
    if (tid < 101) ktn[tid] *= norm2[0];
    if (tid < 11)  kxn[tid] *= norm2[1];
    __syncthreads();

    // ---- T-conv A fragments: kt band scaled x16, packed fp8 e4m3 ----
    long a_t[4];
#pragma unroll
    for (int c = 0; c < 4; ++c) {
        float vv[8];
#pragma unroll
        for (int sl = 0; sl < 8; ++sl) {
            int idx = 32 * c + 8 * g + sl - ln16 - 6;
            vv[sl] = (idx >= 0 && idx <= 100) ? ktn[idx] * 16.0f : 0.0f;
        }
        int lo = __builtin_amdgcn_cvt_pk_fp8_f32(vv[0], vv[1], 0, false);
        lo     = __builtin_amdgcn_cvt_pk_fp8_f32(vv[2], vv[3], lo, true);
        int hi = __builtin_amdgcn_cvt_pk_fp8_f32(vv[4], vv[5], 0, false);
        hi     = __builtin_amdgcn_cvt_pk_fp8_f32(vv[6], vv[7], hi, true);
        a_t[c] = (long)(((unsigned long long)(unsigned)hi << 32) | (unsigned)lo);
    }
    // kx as packed f16 pairs (kxn[11]=0 pad)
    uint kpk[6];
#pragma unroll
    for (int j = 0; j < 6; ++j)
        kpk[j] = __builtin_bit_cast(uint, __builtin_amdgcn_cvt_pkrtz(kxn[2 * j], kxn[2 * j + 1]));

    const float* xb = xg + (size_t)b * T_ * X_;
    const float* yb = yg + (size_t)b * T_ * X_;

    // X-conv of one field, row rr8, cols 4pcg..4pcg+3 -> fp8 ring slot u
    auto xconv = [&](int f, int u, int sb) {
        const ushort* row = &PB[sb][f][rr8][0];
        uint wv[8];
#pragma unroll
        for (int m2 = 0; m2 < 8; ++m2) wv[m2] = *(const uint*)(row + 4 * pcg + 12 + 2 * m2);
        uint sv[7];
#pragma unroll
        for (int j2 = 0; j2 < 7; ++j2) sv[j2] = __builtin_amdgcn_alignbit(wv[j2 + 1], wv[j2], 16);
        float o0 = 0.f, o1 = 0.f, o2 = 0.f, o3 = 0.f;
#pragma unroll
        for (int j2 = 0; j2 < 6; ++j2) {
            o0 = dot2f(kpk[j2], sv[j2], o0);
            o1 = dot2f(kpk[j2], wv[j2 + 1], o1);
            o2 = dot2f(kpk[j2], sv[j2 + 1], o2);
            o3 = dot2f(kpk[j2], wv[j2 + 2], o3);
        }
        int pk8 = __builtin_amdgcn_cvt_pk_fp8_f32(o0, o1, 0, false);
        pk8     = __builtin_amdgcn_cvt_pk_fp8_f32(o2, o3, pk8, true);
        uint pkc   = (uint)pk8;
        uint part1 = (uint)__builtin_amdgcn_update_dpp(0, (int)pkc, 177, 0xF, 0xF, true);
        uint s1v   = __builtin_amdgcn_perm(pkc, part1, sel1);
        uint part2 = (uint)__builtin_amdgcn_update_dpp(0, (int)s1v, 78, 0xF, 0xF, true);
        uint Tt    = __builtin_amdgcn_perm(s1v, part2, sel2);
        *(uint*)((uchar*)&XS[u][f][4 * pcg + cidx] + abyte) = Tt;
    };

    float local = 0.f;
    int gbase = 0;                  // (2*it) % 18
    const int itmax = nm + 8;

    for (int it = 0; it <= itmax; ++it) {
        const int  srcbuf = (it - 1) & 1;
        const int  dstbuf = it & 1;
        const bool xcOK   = (it >= 1) && (it <= nm + 7);
        int uw = gbase + 16 + p01; if (uw >= 18) uw -= 18;

        if (pair != (it & 1)) {
            // ============ loader role: loads + xconv f0-2 + products ============
            const bool doLd = (it <= nm + 6);
            float4 xv[2], yv[2];
            const int  gcol  = x0 - 16 + 4 * kq;
            const bool colOK = (gcol >= 0) && (gcol < X_);
#pragma unroll
            for (int s = 0; s < 2; ++s) {
                int grow = t0 - 56 + 16 * it + 8 * s + 4 * p01 + rhal;
                bool ok = doLd && colOK && (grow >= 0) && (grow < T_);
                xv[s] = ok ? *(const float4*)(xb + (size_t)grow * X_ + gcol) : make_float4(0.f, 0.f, 0.f, 0.f);
                yv[s] = ok ? *(const float4*)(yb + (size_t)grow * X_ + gcol) : make_float4(0.f, 0.f, 0.f, 0.f);
            }
            if (xcOK) { xconv(0, uw, srcbuf); xconv(1, uw, srcbuf); xconv(2, uw, srcbuf); }
            if (doLd) {
#pragma unroll
                for (int s = 0; s < 2; ++s) {
                    int rrs = 8 * s + 4 * p01 + rhal;
                    float4 X = xv[s], Y = yv[s];
                    ushort* p0 = &PB[dstbuf][0][rrs][4 * kq + 2];
                    ushort* p1 = &PB[dstbuf][1][rrs][4 * kq + 2];
                    ushort* p2 = &PB[dstbuf][2][rrs][4 * kq + 2];
                    ushort* p3 = &PB[dstbuf][3][rrs][4 * kq + 2];
                    ushort* p4 = &PB[dstbuf][4][rrs][4 * kq + 2];
                    *(uint*)(p0)     = __builtin_bit_cast(uint, __builtin_amdgcn_cvt_pkrtz(X.x, X.y));
                    *(uint*)(p0 + 2) = __builtin_bit_cast(uint, __builtin_amdgcn_cvt_pkrtz(X.z, X.w));
                    *(uint*)(p1)     = __builtin_bit_cast(uint, __builtin_amdgcn_cvt_pkrtz(Y.x, Y.y));
                    *(uint*)(p1 + 2) = __builtin_bit_cast(uint, __builtin_amdgcn_cvt_pkrtz(Y.z, Y.w));
                    *(uint*)(p2)     = __builtin_bit_cast(uint, __builtin_amdgcn_cvt_pkrtz(X.x * X.x, X.y * X.y));
                    *(uint*)(p2 + 2) = __builtin_bit_cast(uint, __builtin_amdgcn_cvt_pkrtz(X.z * X.z, X.w * X.w));
                    *(uint*)(p3)     = __builtin_bit_cast(uint, __builtin_amdgcn_cvt_pkrtz(Y.x * Y.y, Y.y * Y.y));
                    *(uint*)(p3 + 2) = __builtin_bit_cast(uint, __builtin_amdgcn_cvt_pkrtz(Y.z * Y.z, Y.w * Y.w));
                    *(uint*)(p4)     = __builtin_bit_cast(uint, __builtin_amdgcn_cvt_pkrtz(X.x * Y.x, X.y * Y.y));
                    *(uint*)(p4 + 2) = __builtin_bit_cast(uint, __builtin_amdgcn_cvt_pkrtz(X.z * Y.z, X.w * Y.w));
                }
            }
        } else {
            // ============ MFMA role: xconv f3,f4 + tconv MFMA + pointwise ============
            if (xcOK) { xconv(3, uw, srcbuf); xconv(4, uw, srcbuf); }
            if (it >= 9) {
                const int m = it - 9;
                f32x4 acc[5];
#pragma unroll
                for (int f = 0; f < 5; ++f) { acc[f][0] = 0.f; acc[f][1] = 0.f; acc[f][2] = 0.f; acc[f][3] = 0.f; }
                __builtin_amdgcn_s_setprio(1);
#pragma unroll
                for (int c = 0; c < 4; ++c) {
                    int u = gbase + 4 * c + g; if (u >= 18) u -= 18;
#pragma unroll
                    for (int f = 0; f < 5; ++f) {
                        long bfrag = (long)XS[u][f][16 * p01 + ln16];
                        acc[f] = __builtin_amdgcn_mfma_f32_16x16x32_fp8_fp8(a_t[c], bfrag, acc[f], 0, 0, 0);
                    }
                }
                __builtin_amdgcn_s_setprio(0);
                const float sc = 0.0625f;
#pragma unroll
                for (int r = 0; r < 4; ++r) {
                    int t = t0 + 16 * m + 4 * g + r;
                    if (t < t_end) {
                        float mux = acc[0][r] * sc, muy = acc[1][r] * sc;
                        float vx  = acc[2][r] * sc - mux * mux;
                        float vy  = acc[3][r] * sc - muy * muy;
                        float cxy = acc[4][r] * sc - mux * muy;
                        local += 1.0f - cxy * rsqrtf(vx * vy + 1e-9f);
                    }
                }
            }
        }
        __syncthreads();
        gbase += 2; if (gbase >= 18) gbase -= 18;
    }

    // ---- block reduction ----
#pragma unroll
    for (int off = 32; off >= 1; off >>= 1) local += __shfl_down(local, off);
    if ((tid & 63) == 0) wred[tid >> 6] = local;
    __syncthreads();
    if (tid == 0)
        partial[((size_t)b * SEGS + seg) * NSX + blockIdx.x] =
            wred[0] + wred[1] + wred[2] + wred[3];
}

__global__ __launch_bounds__(256) void coh_reduce(const float* __restrict__ partial,
                                                  float* __restrict__ out) {
    __shared__ float wred[4];
    const int tid = threadIdx.x;
    float s = 0.0f;
    for (int i = tid; i < NBLK; i += 256) s += partial[i];
#pragma unroll
    for (int off = 32; off >= 1; off >>= 1) s += __shfl_down(s, off);
    if ((tid & 63) == 0) wred[tid >> 6] = s;
    __syncthreads();
    if (tid == 0)
        out[0] = (wred[0] + wred[1] + wred[2] + wred[3]) *
                 (1.0f / ((float)B_ * (float)T_ * (float)X_));
}

extern "C" void kernel_launch(void* const* d_in, const int* in_sizes, int n_in,
                              void* d_out, int out_size, void* d_ws, size_t ws_size,
                              hipStream_t stream) {
    const float* x = (const float*)d_in[0];
    const float* y = (const float*)d_in[1];
    float* out = (float*)d_out;
    float* partial = (float*)d_ws;   // NBLK floats = 4 KB

    dim3 grid(NSX, SEGS, B_);        // 16 x 4 x 16 = 1024 blocks
    coh5<<<grid, 256, 0, stream>>>(x, y, partial);
    coh_reduce<<<1, 256, 0, stream>>>(partial, out);
}

// Round 6
// 108.440 us; speedup vs baseline: 1.2562x; 1.2562x over previous
//
#include <hip/hip_runtime.h>
#include <hip/hip_bf16.h>

#define B_   16
#define T_   2500
#define X_   512
#define XT   32
#define SEGS 4
#define SEGR 640
#define NSX  (X_ / XT)            // 16
#define NBLK (B_ * SEGS * NSX)    // 1024
#define PBW  74                   // PB col stride (ushorts) = 37 banks (odd) -> ~2-way reads

typedef __attribute__((ext_vector_type(4))) float f32x4;
typedef _Float16 h2v __attribute__((ext_vector_type(2)));

__device__ __forceinline__ float dot2f(uint kp, uint vp, float c) {
#if __has_builtin(__builtin_amdgcn_fdot2)
    return __builtin_amdgcn_fdot2(__builtin_bit_cast(h2v, kp),
                                  __builtin_bit_cast(h2v, vp), c, false);
#else
    h2v a = __builtin_bit_cast(h2v, kp), b = __builtin_bit_cast(h2v, vp);
    return fmaf((float)a[0], (float)b[0], fmaf((float)a[1], (float)b[1], c));
#endif
}

// Round-6 = round-4 skeleton (1 barrier/iter, wave-pair role alternation,
// fp8 ring, producer owns ALL xconv, single PB with per-wave row ownership)
// + instruction diet:
//   - fp16 products (pkrtz) + v_dot2_f32_f16 11-tap xconv
//   - PB stride 74 ushorts (odd bank stride -> ~2-way xconv reads)
//   - DPP 4x4 byte-transpose -> 1 ds_write_b32 per field (was 4 byte stores @8-way)
//   - float4 coalesced staging (rows kept within the owning wave's 8-row half)
__global__ __launch_bounds__(256, 4) void coh6(const float* __restrict__ xg,
                                               const float* __restrict__ yg,
                                               float* __restrict__ partial)
{
    __shared__ float ktn[104];
    __shared__ float kxn[12];
    __shared__ float norm2[2];
    __shared__ unsigned long long XS[18][5][34];  // fp8 ring: byte rs of [slot][f][col] = row-slot rs
    __shared__ ushort PB[5][16][PBW];             // fp16 products; staged col j at idx j+2
    __shared__ float wred[4];

    const int tid  = threadIdx.x;
    const int lane = tid & 63;
    const int w    = tid >> 6;
    const int g    = lane >> 4;
    const int ln16 = lane & 15;
    const int pair = w >> 1;        // wave-pair 0/1
    const int p01  = w & 1;         // wave within pair
    const int prow = lane & 7;      // xconv: row within wave's 8-row half
    const int pcg  = lane >> 3;     // xconv: 4-col output group
    const int kq   = lane & 15;     // stage: float4 column group
    const int rhal = lane >> 4;     // stage: row within 4-row pass
    const int rr8  = 8 * p01 + prow;

    // DPP 4x4 byte-transpose constants (verified in round 5)
    const uint sel1  = (prow & 1) ? 0x07030602u : 0x01050004u;
    const uint sel2  = (prow & 2) ? 0x07060302u : 0x01000504u;
    const int  cidx  = ((prow & 1) << 1) | ((prow >> 1) & 1);
    const int  abyte = (prow & 4);

    const int x0    = blockIdx.x * XT;
    const int seg   = blockIdx.y;
    const int t0    = seg * SEGR;
    const int t_end = min(t0 + SEGR, T_);
    const int nm    = (t_end - t0 + 15) >> 4;
    const int b     = blockIdx.z;

    // ---- normalized Gaussian tables ----
    if (tid < 104) ktn[tid] = 0.0f;
    if (tid < 12)  kxn[tid] = 0.0f;
    __syncthreads();
    if (tid < 101) { float d = (float)(tid - 50); ktn[tid] = expf(-d * d / (2.0f * 21.0f * 21.0f)); }
    if (tid < 11)  { float d = (float)(tid - 5);  kxn[tid] = expf(-d * d / (2.0f * 11.0f * 11.0f)); }
    __syncthreads();
    if (tid == 0) {
        float s = 0.f; for (int i = 0; i < 101; ++i) s += ktn[i]; norm2[0] = 1.0f / s;
        s = 0.f;       for (int i = 0; i < 11;  ++i) s += kxn[i]; norm2[1] = 1.0f / s;
    }
    __syncthreads();
    if (tid < 101) ktn[tid] *= norm2[0];
    if (tid < 11)  kxn[tid] *= norm2[1];
    __syncthreads();

    // ---- T-conv A fragments: kt band scaled x16, packed fp8 e4m3 (round-4 verbatim) ----
    long a_t[4];
#pragma unroll
    for (int c = 0; c < 4; ++c) {
        float vv[8];
#pragma unroll
        for (int sl = 0; sl < 8; ++sl) {
            int idx = 32 * c + 8 * g + sl - ln16 - 6;
            vv[sl] = (idx >= 0 && idx <= 100) ? ktn[idx] * 16.0f : 0.0f;
        }
        int lo = __builtin_amdgcn_cvt_pk_fp8_f32(vv[0], vv[1], 0, false);
        lo     = __builtin_amdgcn_cvt_pk_fp8_f32(vv[2], vv[3], lo, true);
        int hi = __builtin_amdgcn_cvt_pk_fp8_f32(vv[4], vv[5], 0, false);
        hi     = __builtin_amdgcn_cvt_pk_fp8_f32(vv[6], vv[7], hi, true);
        a_t[c] = (long)(((unsigned long long)(unsigned)hi << 32) | (unsigned)lo);
    }
    // kx as packed f16 pairs (kxn[11] = 0 pad)
    uint kpk[6];
#pragma unroll
    for (int j = 0; j < 6; ++j)
        kpk[j] = __builtin_bit_cast(uint, __builtin_amdgcn_cvt_pkrtz(kxn[2 * j], kxn[2 * j + 1]));

    const float* xb = xg + (size_t)b * T_ * X_;
    const float* yb = yg + (size_t)b * T_ * X_;

    // X-conv of one field, row rr8, output cols 4pcg..4pcg+3 -> fp8 ring slot u.
    // Staged col j lives at PB idx j+2; output col c needs staged 11+c..21+c.
    auto xconv = [&](int f, int u) {
        const ushort* row = &PB[f][rr8][0];
        uint wv[8];
#pragma unroll
        for (int m2 = 0; m2 < 8; ++m2) wv[m2] = *(const uint*)(row + 4 * pcg + 12 + 2 * m2);
        uint sv[7];
#pragma unroll
        for (int j2 = 0; j2 < 7; ++j2) sv[j2] = __builtin_amdgcn_alignbit(wv[j2 + 1], wv[j2], 16);
        float o0 = 0.f, o1 = 0.f, o2 = 0.f, o3 = 0.f;
#pragma unroll
        for (int j2 = 0; j2 < 6; ++j2) {
            o0 = dot2f(kpk[j2], sv[j2], o0);
            o1 = dot2f(kpk[j2], wv[j2 + 1], o1);
            o2 = dot2f(kpk[j2], sv[j2 + 1], o2);
            o3 = dot2f(kpk[j2], wv[j2 + 2], o3);
        }
        int pk8 = __builtin_amdgcn_cvt_pk_fp8_f32(o0, o1, 0, false);
        pk8     = __builtin_amdgcn_cvt_pk_fp8_f32(o2, o3, pk8, true);
        uint pkc   = (uint)pk8;
        uint part1 = (uint)__builtin_amdgcn_update_dpp(0, (int)pkc, 177, 0xF, 0xF, true);
        uint s1v   = __builtin_amdgcn_perm(pkc, part1, sel1);
        uint part2 = (uint)__builtin_amdgcn_update_dpp(0, (int)s1v, 78, 0xF, 0xF, true);
        uint Tt    = __builtin_amdgcn_perm(s1v, part2, sel2);
        *(uint*)((uchar*)&XS[u][f][4 * pcg + cidx] + abyte) = Tt;
    };

    float local = 0.f;
    int gbase = 0;                  // (2*it) % 18
    const int itmax = nm + 8;

    for (int it = 0; it <= itmax; ++it) {
        const bool xcOK = (it >= 1) && (it <= nm + 7);
        int uw = gbase + 16 + p01; if (uw >= 18) uw -= 18;   // slot of group 2(it-1)+p01

        if (pair != (it & 1)) {
            // ============ producer: loads -> xconv(it-1) -> products(it) ============
            const bool doLd  = (it <= nm + 6);
            const int  gcol  = x0 - 16 + 4 * kq;
            const bool colOK = (gcol >= 0) && (gcol < X_);
            float4 xv[2], yv[2];
#pragma unroll
            for (int s = 0; s < 2; ++s) {
                int grow = t0 - 56 + 16 * it + 8 * p01 + 4 * s + rhal;
                bool ok = doLd && colOK && (grow >= 0) && (grow < T_);
                xv[s] = ok ? *(const float4*)(xb + (size_t)grow * X_ + gcol) : make_float4(0.f, 0.f, 0.f, 0.f);
                yv[s] = ok ? *(const float4*)(yb + (size_t)grow * X_ + gcol) : make_float4(0.f, 0.f, 0.f, 0.f);
            }
            if (xcOK) {
                xconv(0, uw); xconv(1, uw); xconv(2, uw); xconv(3, uw); xconv(4, uw);
            }
            if (doLd) {
#pragma unroll
                for (int s = 0; s < 2; ++s) {
                    int rrs = 8 * p01 + 4 * s + rhal;      // wave owns rows 8*p01..8*p01+7
                    float4 X = xv[s], Y = yv[s];
                    ushort* p0 = &PB[0][rrs][4 * kq + 2];
                    ushort* p1 = &PB[1][rrs][4 * kq + 2];
                    ushort* p2 = &PB[2][rrs][4 * kq + 2];
                    ushort* p3 = &PB[3][rrs][4 * kq + 2];
                    ushort* p4 = &PB[4][rrs][4 * kq + 2];
                    *(uint*)(p0)     = __builtin_bit_cast(uint, __builtin_amdgcn_cvt_pkrtz(X.x, X.y));
                    *(uint*)(p0 + 2) = __builtin_bit_cast(uint, __builtin_amdgcn_cvt_pkrtz(X.z, X.w));
                    *(uint*)(p1)     = __builtin_bit_cast(uint, __builtin_amdgcn_cvt_pkrtz(Y.x, Y.y));
                    *(uint*)(p1 + 2) = __builtin_bit_cast(uint, __builtin_amdgcn_cvt_pkrtz(Y.z, Y.w));
                    *(uint*)(p2)     = __builtin_bit_cast(uint, __builtin_amdgcn_cvt_pkrtz(X.x * X.x, X.y * X.y));
                    *(uint*)(p2 + 2) = __builtin_bit_cast(uint, __builtin_amdgcn_cvt_pkrtz(X.z * X.z, X.w * X.w));
                    *(uint*)(p3)     = __builtin_bit_cast(uint, __builtin_amdgcn_cvt_pkrtz(Y.x * Y.x, Y.y * Y.y));
                    *(uint*)(p3 + 2) = __builtin_bit_cast(uint, __builtin_amdgcn_cvt_pkrtz(Y.z * Y.z, Y.w * Y.w));
                    *(uint*)(p4)     = __builtin_bit_cast(uint, __builtin_amdgcn_cvt_pkrtz(X.x * Y.x, X.y * Y.y));
                    *(uint*)(p4 + 2) = __builtin_bit_cast(uint, __builtin_amdgcn_cvt_pkrtz(X.z * Y.z, X.w * Y.w));
                }
            }
        } else if (it >= 9) {
            // ============ consumer: fp8 tconv MFMA + pointwise (round-4 verbatim) ============
            const int m = it - 9;
            f32x4 acc[5];
#pragma unroll
            for (int f = 0; f < 5; ++f) { acc[f][0] = 0.f; acc[f][1] = 0.f; acc[f][2] = 0.f; acc[f][3] = 0.f; }
            __builtin_amdgcn_s_setprio(1);
#pragma unroll
            for (int c = 0; c < 4; ++c) {
                int u = gbase + 4 * c + g; if (u >= 18) u -= 18;   // slot of group 2m+4c+g
#pragma unroll
                for (int f = 0; f < 5; ++f) {
                    long bfrag = (long)XS[u][f][16 * p01 + ln16];
                    acc[f] = __builtin_amdgcn_mfma_f32_16x16x32_fp8_fp8(a_t[c], bfrag, acc[f], 0, 0, 0);
                }
            }
            __builtin_amdgcn_s_setprio(0);
            const float sc = 0.0625f;   // undo kt x16 scaling
#pragma unroll
            for (int r = 0; r < 4; ++r) {
                int t = t0 + 16 * m + 4 * g + r;
                if (t < t_end) {
                    float mux = acc[0][r] * sc, muy = acc[1][r] * sc;
                    float vx  = acc[2][r] * sc - mux * mux;
                    float vy  = acc[3][r] * sc - muy * muy;
                    float cxy = acc[4][r] * sc - mux * muy;
                    local += 1.0f - cxy * rsqrtf(vx * vy + 1e-9f);
                }
            }
        }
        __syncthreads();
        gbase += 2; if (gbase >= 18) gbase -= 18;
    }

    // ---- block reduction ----
#pragma unroll
    for (int off = 32; off >= 1; off >>= 1) local += __shfl_down(local, off);
    if ((tid & 63) == 0) wred[tid >> 6] = local;
    __syncthreads();
    if (tid == 0)
        partial[((size_t)b * SEGS + seg) * NSX + blockIdx.x] =
            wred[0] + wred[1] + wred[2] + wred[3];
}

__global__ __launch_bounds__(256) void coh_reduce(const float* __restrict__ partial,
                                                  float* __restrict__ out) {
    __shared__ float wred[4];
    const int tid = threadIdx.x;
    float s = 0.0f;
    for (int i = tid; i < NBLK; i += 256) s += partial[i];
#pragma unroll
    for (int off = 32; off >= 1; off >>= 1) s += __shfl_down(s, off);
    if ((tid & 63) == 0) wred[tid >> 6] = s;
    __syncthreads();
    if (tid == 0)
        out[0] = (wred[0] + wred[1] + wred[2] + wred[3]) *
                 (1.0f / ((float)B_ * (float)T_ * (float)X_));
}

extern "C" void kernel_launch(void* const* d_in, const int* in_sizes, int n_in,
                              void* d_out, int out_size, void* d_ws, size_t ws_size,
                              hipStream_t stream) {
    const float* x = (const float*)d_in[0];
    const float* y = (const float*)d_in[1];
    float* out = (float*)d_out;
    float* partial = (float*)d_ws;   // NBLK floats = 4 KB

    dim3 grid(NSX, SEGS, B_);        // 16 x 4 x 16 = 1024 blocks
    coh6<<<grid, 256, 0, stream>>>(x, y, partial);
    coh_reduce<<<1, 256, 0, stream>>>(partial, out);
}

// Round 7
// 91.905 us; speedup vs baseline: 1.4822x; 1.1799x over previous
//
#include <hip/hip_runtime.h>
#include <hip/hip_bf16.h>

#define B_   16
#define T_   2500
#define X_   512
#define XT   32
#define SEGS 4
#define SEGR 640
#define NSX  (X_ / XT)            // 16
#define NBLK (B_ * SEGS * NSX)    // 1024

typedef __attribute__((ext_vector_type(4))) float f32x4;

// Round-7 = round-6 skeleton (1 barrier/iter, pair role alternation, fp8 ring,
// 18-slot ring, verified fp8 tconv MFMA) with the X-conv moved to the MFMA pipe:
//  - products stored as fp8 e4m3 in a ping-pong PB (2 x 5 x 16 rows x 72B)
//  - xconv = 5 fp8 MFMAs per producer wave (A = banded kx x16, k-slot convention
//    identical to a_t; B = PB fragment, one aligned ds_read_b64 per field)
//  - D packed via cvt_pk_fp8 + round-5/6-verified DPP 4x4 byte transpose ->
//    one ds_write_b32 per field into the ring (both row-groups, cols split by p01)
// Scales: products x1, kx x16, kt x16 -> acc = 256 x field; folded into pointwise
// (eps' = 1e-9 * 256^2).
__global__ __launch_bounds__(256, 4) void coh7(const float* __restrict__ xg,
                                               const float* __restrict__ yg,
                                               float* __restrict__ partial)
{
    __shared__ float ktn[104];
    __shared__ float kxn[12];
    __shared__ float norm2[2];
    __shared__ unsigned long long XS[18][5][34];   // fp8 ring: byte rs of [slot][f][col] = row-slot
    __shared__ unsigned long long PBq[2][5][16][9]; // fp8 products, ping-pong; 72B rows (col j byte = j)
    __shared__ float wred[4];

    const int tid  = threadIdx.x;
    const int lane = tid & 63;
    const int w    = tid >> 6;
    const int g    = lane >> 4;      // fragment group / stage row
    const int ln16 = lane & 15;      // fragment row-index / stage col
    const int pair = w >> 1;
    const int p01  = w & 1;

    // DPP 4x4 byte-transpose constants (keyed on lane bits 0..2 — identical to r5/r6)
    const uint sel1  = (ln16 & 1) ? 0x07030602u : 0x01050004u;
    const uint sel2  = (ln16 & 2) ? 0x07060302u : 0x01000504u;
    const int  cidx  = ((ln16 & 1) << 1) | ((ln16 >> 1) & 1);
    const int  abyte = (ln16 & 4);
    const int  uhalf = (ln16 >> 3);  // which of the two row-groups this lane's trow is in

    const int x0    = blockIdx.x * XT;
    const int seg   = blockIdx.y;
    const int t0    = seg * SEGR;
    const int t_end = min(t0 + SEGR, T_);
    const int nm    = (t_end - t0 + 15) >> 4;
    const int b     = blockIdx.z;

    // ---- normalized Gaussian tables ----
    if (tid < 104) ktn[tid] = 0.0f;
    if (tid < 12)  kxn[tid] = 0.0f;
    __syncthreads();
    if (tid < 101) { float d = (float)(tid - 50); ktn[tid] = expf(-d * d / (2.0f * 21.0f * 21.0f)); }
    if (tid < 11)  { float d = (float)(tid - 5);  kxn[tid] = expf(-d * d / (2.0f * 11.0f * 11.0f)); }
    __syncthreads();
    if (tid == 0) {
        float s = 0.f; for (int i = 0; i < 101; ++i) s += ktn[i]; norm2[0] = 1.0f / s;
        s = 0.f;       for (int i = 0; i < 11;  ++i) s += kxn[i]; norm2[1] = 1.0f / s;
    }
    __syncthreads();
    if (tid < 101) ktn[tid] *= norm2[0];
    if (tid < 11)  kxn[tid] *= norm2[1];
    __syncthreads();

    // ---- T-conv A fragments: kt band x16, fp8 (round-4 verbatim; verified) ----
    long a_t[4];
#pragma unroll
    for (int c = 0; c < 4; ++c) {
        float vv[8];
#pragma unroll
        for (int sl = 0; sl < 8; ++sl) {
            int idx = 32 * c + 8 * g + sl - ln16 - 6;
            vv[sl] = (idx >= 0 && idx <= 100) ? ktn[idx] * 16.0f : 0.0f;
        }
        int lo = __builtin_amdgcn_cvt_pk_fp8_f32(vv[0], vv[1], 0, false);
        lo     = __builtin_amdgcn_cvt_pk_fp8_f32(vv[2], vv[3], lo, true);
        int hi = __builtin_amdgcn_cvt_pk_fp8_f32(vv[4], vv[5], 0, false);
        hi     = __builtin_amdgcn_cvt_pk_fp8_f32(vv[6], vv[7], hi, true);
        a_t[c] = (long)(((unsigned long long)(unsigned)hi << 32) | (unsigned)lo);
    }
    // ---- X-conv A fragment: kx band x16, fp8. A[m][k] = kx[k-m-3] (k = 8g+sl) ----
    long a_x;
    {
        float vv[8];
#pragma unroll
        for (int sl = 0; sl < 8; ++sl) {
            int idx = 8 * g + sl - ln16 - 3;
            vv[sl] = (idx >= 0 && idx <= 10) ? kxn[idx] * 16.0f : 0.0f;
        }
        int lo = __builtin_amdgcn_cvt_pk_fp8_f32(vv[0], vv[1], 0, false);
        lo     = __builtin_amdgcn_cvt_pk_fp8_f32(vv[2], vv[3], lo, true);
        int hi = __builtin_amdgcn_cvt_pk_fp8_f32(vv[4], vv[5], 0, false);
        hi     = __builtin_amdgcn_cvt_pk_fp8_f32(vv[6], vv[7], hi, true);
        a_x = (long)(((unsigned long long)(unsigned)hi << 32) | (unsigned)lo);
    }

    const float* xb = xg + (size_t)b * T_ * X_;
    const float* yb = yg + (size_t)b * T_ * X_;

    float local = 0.f;
    int gbase = 0;                  // (2*it) % 18
    const int itmax = nm + 8;

    for (int it = 0; it <= itmax; ++it) {
        const bool xcOK = (it >= 1) && (it <= nm + 7);

        if (pair != (it & 1)) {
            // ============ producer: loads -> xconv-MFMA(it-1) -> products(it) ============
            const bool doLd  = (it <= nm + 6);
            const int  gcol  = x0 - 16 + 4 * ln16;            // stage col group (float4)
            const bool colOK = (gcol >= 0) && (gcol < X_);
            float4 xv[2], yv[2];
#pragma unroll
            for (int s = 0; s < 2; ++s) {
                int grow = t0 - 56 + 16 * it + 8 * p01 + 4 * s + g;
                bool ok = doLd && colOK && (grow >= 0) && (grow < T_);
                xv[s] = ok ? *(const float4*)(xb + (size_t)grow * X_ + gcol) : make_float4(0.f, 0.f, 0.f, 0.f);
                yv[s] = ok ? *(const float4*)(yb + (size_t)grow * X_ + gcol) : make_float4(0.f, 0.f, 0.f, 0.f);
            }
            if (xcOK) {
                // ring slots for chunk it-1 (row-groups 2(it-1), 2(it-1)+1)
                int u0 = gbase + 16; if (u0 >= 18) u0 -= 18;
                int u1 = u0 + 1;     if (u1 >= 18) u1 -= 18;
                const int uu = uhalf ? u1 : u0;
                const int sb = (it - 1) & 1;
#pragma unroll
                for (int f = 0; f < 5; ++f) {
                    // B[k][n]: n = ln16 (t-row), k = 8g+sl <-> staged byte 16*p01+8+k
                    long bfrag = (long)PBq[sb][f][ln16][1 + 2 * p01 + g];
                    f32x4 z; z[0] = 0.f; z[1] = 0.f; z[2] = 0.f; z[3] = 0.f;
                    f32x4 d = __builtin_amdgcn_mfma_f32_16x16x32_fp8_fp8(a_x, bfrag, z, 0, 0, 0);
                    // lane holds outcols 16*p01+4g+r (r=0..3) of t-row ln16; pack + 4x4 transpose
                    int pk = __builtin_amdgcn_cvt_pk_fp8_f32(d[0], d[1], 0, false);
                    pk     = __builtin_amdgcn_cvt_pk_fp8_f32(d[2], d[3], pk, true);
                    uint pkc   = (uint)pk;
                    uint part1 = (uint)__builtin_amdgcn_update_dpp(0, (int)pkc, 177, 0xF, 0xF, true);
                    uint s1v   = __builtin_amdgcn_perm(pkc, part1, sel1);
                    uint part2 = (uint)__builtin_amdgcn_update_dpp(0, (int)s1v, 78, 0xF, 0xF, true);
                    uint Tt    = __builtin_amdgcn_perm(s1v, part2, sel2);
                    *(uint*)((uchar*)&XS[uu][f][16 * p01 + 4 * g + cidx] + abyte) = Tt;
                }
            }
            if (doLd) {
                const int db = it & 1;
#pragma unroll
                for (int s = 0; s < 2; ++s) {
                    int rrs = 8 * p01 + 4 * s + g;
                    float4 X = xv[s], Y = yv[s];
                    int q0 = __builtin_amdgcn_cvt_pk_fp8_f32(X.x, X.y, 0, false);
                    q0     = __builtin_amdgcn_cvt_pk_fp8_f32(X.z, X.w, q0, true);
                    int q1 = __builtin_amdgcn_cvt_pk_fp8_f32(Y.x, Y.y, 0, false);
                    q1     = __builtin_amdgcn_cvt_pk_fp8_f32(Y.z, Y.w, q1, true);
                    int q2 = __builtin_amdgcn_cvt_pk_fp8_f32(X.x * X.x, X.y * X.y, 0, false);
                    q2     = __builtin_amdgcn_cvt_pk_fp8_f32(X.z * X.z, X.w * X.w, q2, true);
                    int q3 = __builtin_amdgcn_cvt_pk_fp8_f32(Y.x * Y.x, Y.y * Y.y, 0, false);
                    q3     = __builtin_amdgcn_cvt_pk_fp8_f32(Y.z * Y.z, Y.w * Y.w, q3, true);
                    int q4 = __builtin_amdgcn_cvt_pk_fp8_f32(X.x * Y.x, X.y * Y.y, 0, false);
                    q4     = __builtin_amdgcn_cvt_pk_fp8_f32(X.z * Y.z, X.w * Y.w, q4, true);
                    *(uint*)((uchar*)&PBq[db][0][rrs][0] + 4 * ln16) = (uint)q0;
                    *(uint*)((uchar*)&PBq[db][1][rrs][0] + 4 * ln16) = (uint)q1;
                    *(uint*)((uchar*)&PBq[db][2][rrs][0] + 4 * ln16) = (uint)q2;
                    *(uint*)((uchar*)&PBq[db][3][rrs][0] + 4 * ln16) = (uint)q3;
                    *(uint*)((uchar*)&PBq[db][4][rrs][0] + 4 * ln16) = (uint)q4;
                }
            }
        } else if (it >= 9) {
            // ============ consumer: fp8 tconv MFMA + pointwise (round-4/6 verbatim) ============
            const int m = it - 9;
            f32x4 acc[5];
#pragma unroll
            for (int f = 0; f < 5; ++f) { acc[f][0] = 0.f; acc[f][1] = 0.f; acc[f][2] = 0.f; acc[f][3] = 0.f; }
            __builtin_amdgcn_s_setprio(1);
#pragma unroll
            for (int c = 0; c < 4; ++c) {
                int u = gbase + 4 * c + g; if (u >= 18) u -= 18;   // slot of row-group 2m+4c+g
#pragma unroll
                for (int f = 0; f < 5; ++f) {
                    long bfrag = (long)XS[u][f][16 * p01 + ln16];
                    acc[f] = __builtin_amdgcn_mfma_f32_16x16x32_fp8_fp8(a_t[c], bfrag, acc[f], 0, 0, 0);
                }
            }
            __builtin_amdgcn_s_setprio(0);
            const float s_ = 1.0f / 256.0f;     // undo kt(16) * kx(16) scaling, folded
#pragma unroll
            for (int r = 0; r < 4; ++r) {
                int t = t0 + 16 * m + 4 * g + r;
                if (t < t_end) {
                    float a0 = acc[0][r], a1 = acc[1][r];
                    float sa0 = a0 * s_, sa1 = a1 * s_;
                    float cov = fmaf(-sa0, a1, acc[4][r]);
                    float vx  = fmaf(-sa0, a0, acc[2][r]);
                    float vy  = fmaf(-sa1, a1, acc[3][r]);
                    local += 1.0f - cov * rsqrtf(fmaf(vx, vy, 6.5536e-5f));
                }
            }
        }
        __syncthreads();
        gbase += 2; if (gbase >= 18) gbase -= 18;
    }

    // ---- block reduction ----
#pragma unroll
    for (int off = 32; off >= 1; off >>= 1) local += __shfl_down(local, off);
    if ((tid & 63) == 0) wred[tid >> 6] = local;
    __syncthreads();
    if (tid == 0)
        partial[((size_t)b * SEGS + seg) * NSX + blockIdx.x] =
            wred[0] + wred[1] + wred[2] + wred[3];
}

__global__ __launch_bounds__(256) void coh_reduce(const float* __restrict__ partial,
                                                  float* __restrict__ out) {
    __shared__ float wred[4];
    const int tid = threadIdx.x;
    float s = 0.0f;
    for (int i = tid; i < NBLK; i += 256) s += partial[i];
#pragma unroll
    for (int off = 32; off >= 1; off >>= 1) s += __shfl_down(s, off);
    if ((tid & 63) == 0) wred[tid >> 6] = s;
    __syncthreads();
    if (tid == 0)
        out[0] = (wred[0] + wred[1] + wred[2] + wred[3]) *
                 (1.0f / ((float)B_ * (float)T_ * (float)X_));
}

extern "C" void kernel_launch(void* const* d_in, const int* in_sizes, int n_in,
                              void* d_out, int out_size, void* d_ws, size_t ws_size,
                              hipStream_t stream) {
    const float* x = (const float*)d_in[0];
    const float* y = (const float*)d_in[1];
    float* out = (float*)d_out;
    float* partial = (float*)d_ws;   // NBLK floats = 4 KB

    dim3 grid(NSX, SEGS, B_);        // 16 x 4 x 16 = 1024 blocks
    coh7<<<grid, 256, 0, stream>>>(x, y, partial);
    coh_reduce<<<1, 256, 0, stream>>>(partial, out);
}

// Round 8
// 91.032 us; speedup vs baseline: 1.4964x; 1.0096x over previous
//
#include <hip/hip_runtime.h>
#include <hip/hip_bf16.h>

#define B_   16
#define T_   2500
#define X_   512
#define XT   32
#define SEGS 4
#define SEGR 640
#define NSX  (X_ / XT)            // 16
#define NBLK (B_ * SEGS * NSX)    // 1024

typedef __attribute__((ext_vector_type(4))) float f32x4;

// Round-8 = round-7 dataflow (verified: 18-slot fp8 ring, banded fp8 MFMA x/t-conv,
// DPP 4x4 transpose ring writes, scale 16*16=256 folded into pointwise) with the
// SCHEDULE changed:
//  - static roles: pair 0 always produces, pair 1 always consumes (no alternation)
//  - T14 async split: producer issues chunk it+1's global loads at the END of its
//    turn; products(it) consume loads issued one full iteration earlier -> the
//    ~700cy HBM/L2 latency hides under barrier + xconv instead of stalling
//  - per-role loop duplication (disjoint reg live ranges: a_x+staging vs a_t+acc)
//  - consumer s_setprio removed (producers are the critical path)
__global__ __launch_bounds__(256, 4) void coh8(const float* __restrict__ xg,
                                               const float* __restrict__ yg,
                                               float* __restrict__ partial)
{
    __shared__ float ktn[104];
    __shared__ float kxn[12];
    __shared__ float norm2[2];
    __shared__ unsigned long long XS[18][5][34];    // fp8 ring: byte rs of [slot][f][col] = row-slot
    __shared__ unsigned long long PBq[2][5][16][9]; // fp8 products ping-pong; 72B rows (byte j = staged col j)
    __shared__ float wred[4];

    const int tid  = threadIdx.x;
    const int lane = tid & 63;
    const int w    = tid >> 6;
    const int g    = lane >> 4;
    const int ln16 = lane & 15;
    const int pair = w >> 1;
    const int p01  = w & 1;

    const int x0    = blockIdx.x * XT;
    const int seg   = blockIdx.y;
    const int t0    = seg * SEGR;
    const int t_end = min(t0 + SEGR, T_);
    const int nm    = (t_end - t0 + 15) >> 4;
    const int b     = blockIdx.z;
    const int itmax = nm + 8;

    // ---- normalized Gaussian tables ----
    if (tid < 104) ktn[tid] = 0.0f;
    if (tid < 12)  kxn[tid] = 0.0f;
    __syncthreads();
    if (tid < 101) { float d = (float)(tid - 50); ktn[tid] = expf(-d * d / (2.0f * 21.0f * 21.0f)); }
    if (tid < 11)  { float d = (float)(tid - 5);  kxn[tid] = expf(-d * d / (2.0f * 11.0f * 11.0f)); }
    __syncthreads();
    if (tid == 0) {
        float s = 0.f; for (int i = 0; i < 101; ++i) s += ktn[i]; norm2[0] = 1.0f / s;
        s = 0.f;       for (int i = 0; i < 11;  ++i) s += kxn[i]; norm2[1] = 1.0f / s;
    }
    __syncthreads();
    if (tid < 101) ktn[tid] *= norm2[0];
    if (tid < 11)  kxn[tid] *= norm2[1];
    __syncthreads();

    const float* xb = xg + (size_t)b * T_ * X_;
    const float* yb = yg + (size_t)b * T_ * X_;

    float local = 0.f;

    if (pair == 0) {
        // ===================== producer loop =====================
        // X-conv A fragment: kx band x16, fp8. A[m][k] = kx[k-m-3], k = 8g+sl.
        long a_x;
        {
            float vv[8];
#pragma unroll
            for (int sl = 0; sl < 8; ++sl) {
                int idx = 8 * g + sl - ln16 - 3;
                vv[sl] = (idx >= 0 && idx <= 10) ? kxn[idx] * 16.0f : 0.0f;
            }
            int lo = __builtin_amdgcn_cvt_pk_fp8_f32(vv[0], vv[1], 0, false);
            lo     = __builtin_amdgcn_cvt_pk_fp8_f32(vv[2], vv[3], lo, true);
            int hi = __builtin_amdgcn_cvt_pk_fp8_f32(vv[4], vv[5], 0, false);
            hi     = __builtin_amdgcn_cvt_pk_fp8_f32(vv[6], vv[7], hi, true);
            a_x = (long)(((unsigned long long)(unsigned)hi << 32) | (unsigned)lo);
        }
        // DPP 4x4 byte-transpose constants (verified r5-r7)
        const uint sel1  = (ln16 & 1) ? 0x07030602u : 0x01050004u;
        const uint sel2  = (ln16 & 2) ? 0x07060302u : 0x01000504u;
        const int  cidx  = ((ln16 & 1) << 1) | ((ln16 >> 1) & 1);
        const int  abyte = (ln16 & 4);
        const int  uhalf = (ln16 >> 3);

        const int  gcol  = x0 - 16 + 4 * ln16;
        const bool colOK = (gcol >= 0) && (gcol < X_);

        float4 xv[2], yv[2];
        // prologue: issue loads for chunk 0
#pragma unroll
        for (int s = 0; s < 2; ++s) {
            int grow = t0 - 56 + 8 * p01 + 4 * s + g;
            bool ok = colOK && (grow >= 0) && (grow < T_);
            xv[s] = ok ? *(const float4*)(xb + (size_t)grow * X_ + gcol) : make_float4(0.f, 0.f, 0.f, 0.f);
            yv[s] = ok ? *(const float4*)(yb + (size_t)grow * X_ + gcol) : make_float4(0.f, 0.f, 0.f, 0.f);
        }

        int gbase = 0;
        for (int it = 0; it <= itmax; ++it) {
            // ---- xconv-MFMA of chunk it-1 -> ring (loads for it keep flying) ----
            if (it >= 1 && it <= nm + 7) {
                int u0 = gbase + 16; if (u0 >= 18) u0 -= 18;
                int u1 = u0 + 1;     if (u1 >= 18) u1 -= 18;
                const int uu = uhalf ? u1 : u0;
                const int sb = (it - 1) & 1;
#pragma unroll
                for (int f = 0; f < 5; ++f) {
                    long bfrag = (long)PBq[sb][f][ln16][1 + 2 * p01 + g];
                    f32x4 z; z[0] = 0.f; z[1] = 0.f; z[2] = 0.f; z[3] = 0.f;
                    f32x4 d = __builtin_amdgcn_mfma_f32_16x16x32_fp8_fp8(a_x, bfrag, z, 0, 0, 0);
                    int pk = __builtin_amdgcn_cvt_pk_fp8_f32(d[0], d[1], 0, false);
                    pk     = __builtin_amdgcn_cvt_pk_fp8_f32(d[2], d[3], pk, true);
                    uint pkc   = (uint)pk;
                    uint part1 = (uint)__builtin_amdgcn_update_dpp(0, (int)pkc, 177, 0xF, 0xF, true);
                    uint s1v   = __builtin_amdgcn_perm(pkc, part1, sel1);
                    uint part2 = (uint)__builtin_amdgcn_update_dpp(0, (int)s1v, 78, 0xF, 0xF, true);
                    uint Tt    = __builtin_amdgcn_perm(s1v, part2, sel2);
                    *(uint*)((uchar*)&XS[uu][f][16 * p01 + 4 * g + cidx] + abyte) = Tt;
                }
            }
            // ---- products of chunk it (consume prefetched loads) ----
            if (it <= nm + 6) {
                const int db = it & 1;
#pragma unroll
                for (int s = 0; s < 2; ++s) {
                    int rrs = 8 * p01 + 4 * s + g;
                    float4 X = xv[s], Y = yv[s];
                    int q0 = __builtin_amdgcn_cvt_pk_fp8_f32(X.x, X.y, 0, false);
                    q0     = __builtin_amdgcn_cvt_pk_fp8_f32(X.z, X.w, q0, true);
                    int q1 = __builtin_amdgcn_cvt_pk_fp8_f32(Y.x, Y.y, 0, false);
                    q1     = __builtin_amdgcn_cvt_pk_fp8_f32(Y.z, Y.w, q1, true);
                    int q2 = __builtin_amdgcn_cvt_pk_fp8_f32(X.x * X.x, X.y * X.y, 0, false);
                    q2     = __builtin_amdgcn_cvt_pk_fp8_f32(X.z * X.z, X.w * X.w, q2, true);
                    int q3 = __builtin_amdgcn_cvt_pk_fp8_f32(Y.x * Y.x, Y.y * Y.y, 0, false);
                    q3     = __builtin_amdgcn_cvt_pk_fp8_f32(Y.z * Y.z, Y.w * Y.w, q3, true);
                    int q4 = __builtin_amdgcn_cvt_pk_fp8_f32(X.x * Y.x, X.y * Y.y, 0, false);
                    q4     = __builtin_amdgcn_cvt_pk_fp8_f32(X.z * Y.z, X.w * Y.w, q4, true);
                    *(uint*)((uchar*)&PBq[db][0][rrs][0] + 4 * ln16) = (uint)q0;
                    *(uint*)((uchar*)&PBq[db][1][rrs][0] + 4 * ln16) = (uint)q1;
                    *(uint*)((uchar*)&PBq[db][2][rrs][0] + 4 * ln16) = (uint)q2;
                    *(uint*)((uchar*)&PBq[db][3][rrs][0] + 4 * ln16) = (uint)q3;
                    *(uint*)((uchar*)&PBq[db][4][rrs][0] + 4 * ln16) = (uint)q4;
                }
            }
            // ---- issue loads for chunk it+1 (in flight across the barrier) ----
            if (it + 1 <= nm + 6) {
#pragma unroll
                for (int s = 0; s < 2; ++s) {
                    int grow = t0 - 56 + 16 * (it + 1) + 8 * p01 + 4 * s + g;
                    bool ok = colOK && (grow >= 0) && (grow < T_);
                    xv[s] = ok ? *(const float4*)(xb + (size_t)grow * X_ + gcol) : make_float4(0.f, 0.f, 0.f, 0.f);
                    yv[s] = ok ? *(const float4*)(yb + (size_t)grow * X_ + gcol) : make_float4(0.f, 0.f, 0.f, 0.f);
                }
            }
            __syncthreads();
            gbase += 2; if (gbase >= 18) gbase -= 18;
        }
    } else {
        // ===================== consumer loop =====================
        // T-conv A fragments: kt band x16, fp8 (round-4 verbatim; verified)
        long a_t[4];
#pragma unroll
        for (int c = 0; c < 4; ++c) {
            float vv[8];
#pragma unroll
            for (int sl = 0; sl < 8; ++sl) {
                int idx = 32 * c + 8 * g + sl - ln16 - 6;
                vv[sl] = (idx >= 0 && idx <= 100) ? ktn[idx] * 16.0f : 0.0f;
            }
            int lo = __builtin_amdgcn_cvt_pk_fp8_f32(vv[0], vv[1], 0, false);
            lo     = __builtin_amdgcn_cvt_pk_fp8_f32(vv[2], vv[3], lo, true);
            int hi = __builtin_amdgcn_cvt_pk_fp8_f32(vv[4], vv[5], 0, false);
            hi     = __builtin_amdgcn_cvt_pk_fp8_f32(vv[6], vv[7], hi, true);
            a_t[c] = (long)(((unsigned long long)(unsigned)hi << 32) | (unsigned)lo);
        }

        int gbase = 0;
        for (int it = 0; it <= itmax; ++it) {
            if (it >= 9) {
                const int m = it - 9;
                f32x4 acc[5];
#pragma unroll
                for (int f = 0; f < 5; ++f) { acc[f][0] = 0.f; acc[f][1] = 0.f; acc[f][2] = 0.f; acc[f][3] = 0.f; }
#pragma unroll
                for (int c = 0; c < 4; ++c) {
                    int u = gbase + 4 * c + g; if (u >= 18) u -= 18;   // slot of row-group 2m+4c+g
#pragma unroll
                    for (int f = 0; f < 5; ++f) {
                        long bfrag = (long)XS[u][f][16 * p01 + ln16];
                        acc[f] = __builtin_amdgcn_mfma_f32_16x16x32_fp8_fp8(a_t[c], bfrag, acc[f], 0, 0, 0);
                    }
                }
                const float s_ = 1.0f / 256.0f;   // undo kt(16)*kx(16) scaling
#pragma unroll
                for (int r = 0; r < 4; ++r) {
                    int t = t0 + 16 * m + 4 * g + r;
                    if (t < t_end) {
                        float a0 = acc[0][r], a1 = acc[1][r];
                        float sa0 = a0 * s_, sa1 = a1 * s_;
                        float cov = fmaf(-sa0, a1, acc[4][r]);
                        float vx  = fmaf(-sa0, a0, acc[2][r]);
                        float vy  = fmaf(-sa1, a1, acc[3][r]);
                        local += 1.0f - cov * rsqrtf(fmaf(vx, vy, 6.5536e-5f));
                    }
                }
            }
            __syncthreads();
            gbase += 2; if (gbase >= 18) gbase -= 18;
        }
    }

    // ---- block reduction ----
#pragma unroll
    for (int off = 32; off >= 1; off >>= 1) local += __shfl_down(local, off);
    if ((tid & 63) == 0) wred[tid >> 6] = local;
    __syncthreads();
    if (tid == 0)
        partial[((size_t)b * SEGS + seg) * NSX + blockIdx.x] =
            wred[0] + wred[1] + wred[2] + wred[3];
}

__global__ __launch_bounds__(256) void coh_reduce(const float* __restrict__ partial,
                                                  float* __restrict__ out) {
    __shared__ float wred[4];
    const int tid = threadIdx.x;
    float s = 0.0f;
    for (int i = tid; i < NBLK; i += 256) s += partial[i];
#pragma unroll
    for (int off = 32; off >= 1; off >>= 1) s += __shfl_down(s, off);
    if ((tid & 63) == 0) wred[tid >> 6] = s;
    __syncthreads();
    if (tid == 0)
        out[0] = (wred[0] + wred[1] + wred[2] + wred[3]) *
                 (1.0f / ((float)B_ * (float)T_ * (float)X_));
}

extern "C" void kernel_launch(void* const* d_in, const int* in_sizes, int n_in,
                              void* d_out, int out_size, void* d_ws, size_t ws_size,
                              hipStream_t stream) {
    const float* x = (const float*)d_in[0];
    const float* y = (const float*)d_in[1];
    float* out = (float*)d_out;
    float* partial = (float*)d_ws;   // NBLK floats = 4 KB

    dim3 grid(NSX, SEGS, B_);        // 16 x 4 x 16 = 1024 blocks
    coh8<<<grid, 256, 0, stream>>>(x, y, partial);
    coh_reduce<<<1, 256, 0, stream>>>(partial, out);
}

// Round 9
// 61.493 us; speedup vs baseline: 2.2152x; 1.4804x over previous
//
#include <hip/hip_runtime.h>
#include <hip/hip_bf16.h>

#define B_   16
#define T_   2500
#define X_   512
#define XT   32
#define SEGS 4
#define SEGR 640
#define NSX  (X_ / XT)            // 16
#define NBLK (B_ * SEGS * NSX)    // 1024

typedef __attribute__((ext_vector_type(4))) float f32x4;

// Raw barrier: drain LDS (lgkmcnt) only, leave global loads (vmcnt) in flight.
// Single asm block so the wait and the barrier cannot be separated; "memory"
// clobber orders all LDS/global memory *operations* across it while letting
// issued loads complete later (compiler inserts vmcnt at first register use).
__device__ __forceinline__ void barrier_lgkm() {
    asm volatile("s_waitcnt lgkmcnt(0)\n\ts_barrier" ::: "memory");
}

// Round-9 = round-8 dataflow byte-for-byte (18-slot fp8 ring, banded fp8 MFMA
// x/t-conv, DPP 4x4 transpose ring writes, static producer/consumer pairs,
// 1-iteration load prefetch) with two schedule/locality grafts:
//  - barrier_lgkm() instead of __syncthreads(): kills the vmcnt(0) drain at the
//    barrier, so the prefetched loads genuinely fly across it (T4 principle)
//  - bijective XCD swizzle (nwg=1024 % 8 == 0): each XCD owns a contiguous
//    128-block chunk -> x-halo and seg-halo re-reads become L2 hits
__global__ __launch_bounds__(256, 4) void coh9(const float* __restrict__ xg,
                                               const float* __restrict__ yg,
                                               float* __restrict__ partial)
{
    __shared__ float ktn[104];
    __shared__ float kxn[12];
    __shared__ float norm2[2];
    __shared__ unsigned long long XS[18][5][34];    // fp8 ring: byte rs of [slot][f][col] = row-slot
    __shared__ unsigned long long PBq[2][5][16][9]; // fp8 products ping-pong; 72B rows
    __shared__ float wred[4];

    const int tid  = threadIdx.x;
    const int lane = tid & 63;
    const int w    = tid >> 6;
    const int g    = lane >> 4;
    const int ln16 = lane & 15;
    const int pair = w >> 1;
    const int p01  = w & 1;

    // ---- XCD-aware bijective block swizzle (1024 blocks, 8 XCDs) ----
    const int bid = blockIdx.x;
    const int wid = (bid & 7) * (NBLK / 8) + (bid >> 3);
    const int xt  = wid & 15;
    const int seg = (wid >> 4) & 3;
    const int b   = wid >> 6;

    const int x0    = xt * XT;
    const int t0    = seg * SEGR;
    const int t_end = min(t0 + SEGR, T_);
    const int nm    = (t_end - t0 + 15) >> 4;
    const int itmax = nm + 8;

    // ---- normalized Gaussian tables ----
    if (tid < 104) ktn[tid] = 0.0f;
    if (tid < 12)  kxn[tid] = 0.0f;
    __syncthreads();
    if (tid < 101) { float d = (float)(tid - 50); ktn[tid] = expf(-d * d / (2.0f * 21.0f * 21.0f)); }
    if (tid < 11)  { float d = (float)(tid - 5);  kxn[tid] = expf(-d * d / (2.0f * 11.0f * 11.0f)); }
    __syncthreads();
    if (tid == 0) {
        float s = 0.f; for (int i = 0; i < 101; ++i) s += ktn[i]; norm2[0] = 1.0f / s;
        s = 0.f;       for (int i = 0; i < 11;  ++i) s += kxn[i]; norm2[1] = 1.0f / s;
    }
    __syncthreads();
    if (tid < 101) ktn[tid] *= norm2[0];
    if (tid < 11)  kxn[tid] *= norm2[1];
    __syncthreads();

    const float* xb = xg + (size_t)b * T_ * X_;
    const float* yb = yg + (size_t)b * T_ * X_;

    float local = 0.f;

    if (pair == 0) {
        // ===================== producer loop =====================
        long a_x;
        {
            float vv[8];
#pragma unroll
            for (int sl = 0; sl < 8; ++sl) {
                int idx = 8 * g + sl - ln16 - 3;
                vv[sl] = (idx >= 0 && idx <= 10) ? kxn[idx] * 16.0f : 0.0f;
            }
            int lo = __builtin_amdgcn_cvt_pk_fp8_f32(vv[0], vv[1], 0, false);
            lo     = __builtin_amdgcn_cvt_pk_fp8_f32(vv[2], vv[3], lo, true);
            int hi = __builtin_amdgcn_cvt_pk_fp8_f32(vv[4], vv[5], 0, false);
            hi     = __builtin_amdgcn_cvt_pk_fp8_f32(vv[6], vv[7], hi, true);
            a_x = (long)(((unsigned long long)(unsigned)hi << 32) | (unsigned)lo);
        }
        // DPP 4x4 byte-transpose constants (verified r5-r8)
        const uint sel1  = (ln16 & 1) ? 0x07030602u : 0x01050004u;
        const uint sel2  = (ln16 & 2) ? 0x07060302u : 0x01000504u;
        const int  cidx  = ((ln16 & 1) << 1) | ((ln16 >> 1) & 1);
        const int  abyte = (ln16 & 4);
        const int  uhalf = (ln16 >> 3);

        const int  gcol  = x0 - 16 + 4 * ln16;
        const bool colOK = (gcol >= 0) && (gcol < X_);

        float4 xv[2], yv[2];
        // prologue: issue loads for chunk 0
#pragma unroll
        for (int s = 0; s < 2; ++s) {
            int grow = t0 - 56 + 8 * p01 + 4 * s + g;
            bool ok = colOK && (grow >= 0) && (grow < T_);
            xv[s] = ok ? *(const float4*)(xb + (size_t)grow * X_ + gcol) : make_float4(0.f, 0.f, 0.f, 0.f);
            yv[s] = ok ? *(const float4*)(yb + (size_t)grow * X_ + gcol) : make_float4(0.f, 0.f, 0.f, 0.f);
        }

        int gbase = 0;
        for (int it = 0; it <= itmax; ++it) {
            // ---- xconv-MFMA of chunk it-1 -> ring (loads for it keep flying) ----
            if (it >= 1 && it <= nm + 7) {
                int u0 = gbase + 16; if (u0 >= 18) u0 -= 18;
                int u1 = u0 + 1;     if (u1 >= 18) u1 -= 18;
                const int uu = uhalf ? u1 : u0;
                const int sb = (it - 1) & 1;
#pragma unroll
                for (int f = 0; f < 5; ++f) {
                    long bfrag = (long)PBq[sb][f][ln16][1 + 2 * p01 + g];
                    f32x4 z; z[0] = 0.f; z[1] = 0.f; z[2] = 0.f; z[3] = 0.f;
                    f32x4 d = __builtin_amdgcn_mfma_f32_16x16x32_fp8_fp8(a_x, bfrag, z, 0, 0, 0);
                    int pk = __builtin_amdgcn_cvt_pk_fp8_f32(d[0], d[1], 0, false);
                    pk     = __builtin_amdgcn_cvt_pk_fp8_f32(d[2], d[3], pk, true);
                    uint pkc   = (uint)pk;
                    uint part1 = (uint)__builtin_amdgcn_update_dpp(0, (int)pkc, 177, 0xF, 0xF, true);
                    uint s1v   = __builtin_amdgcn_perm(pkc, part1, sel1);
                    uint part2 = (uint)__builtin_amdgcn_update_dpp(0, (int)s1v, 78, 0xF, 0xF, true);
                    uint Tt    = __builtin_amdgcn_perm(s1v, part2, sel2);
                    *(uint*)((uchar*)&XS[uu][f][16 * p01 + 4 * g + cidx] + abyte) = Tt;
                }
            }
            // ---- products of chunk it (consume loads issued one iteration ago) ----
            if (it <= nm + 6) {
                const int db = it & 1;
#pragma unroll
                for (int s = 0; s < 2; ++s) {
                    int rrs = 8 * p01 + 4 * s + g;
                    float4 X = xv[s], Y = yv[s];
                    int q0 = __builtin_amdgcn_cvt_pk_fp8_f32(X.x, X.y, 0, false);
                    q0     = __builtin_amdgcn_cvt_pk_fp8_f32(X.z, X.w, q0, true);
                    int q1 = __builtin_amdgcn_cvt_pk_fp8_f32(Y.x, Y.y, 0, false);
                    q1     = __builtin_amdgcn_cvt_pk_fp8_f32(Y.z, Y.w, q1, true);
                    int q2 = __builtin_amdgcn_cvt_pk_fp8_f32(X.x * X.x, X.y * X.y, 0, false);
                    q2     = __builtin_amdgcn_cvt_pk_fp8_f32(X.z * X.z, X.w * X.w, q2, true);
                    int q3 = __builtin_amdgcn_cvt_pk_fp8_f32(Y.x * Y.x, Y.y * Y.y, 0, false);
                    q3     = __builtin_amdgcn_cvt_pk_fp8_f32(Y.z * Y.z, Y.w * Y.w, q3, true);
                    int q4 = __builtin_amdgcn_cvt_pk_fp8_f32(X.x * Y.x, X.y * Y.y, 0, false);
                    q4     = __builtin_amdgcn_cvt_pk_fp8_f32(X.z * Y.z, X.w * Y.w, q4, true);
                    *(uint*)((uchar*)&PBq[db][0][rrs][0] + 4 * ln16) = (uint)q0;
                    *(uint*)((uchar*)&PBq[db][1][rrs][0] + 4 * ln16) = (uint)q1;
                    *(uint*)((uchar*)&PBq[db][2][rrs][0] + 4 * ln16) = (uint)q2;
                    *(uint*)((uchar*)&PBq[db][3][rrs][0] + 4 * ln16) = (uint)q3;
                    *(uint*)((uchar*)&PBq[db][4][rrs][0] + 4 * ln16) = (uint)q4;
                }
            }
            // ---- issue loads for chunk it+1 (stay in flight across the raw barrier) ----
            if (it + 1 <= nm + 6) {
#pragma unroll
                for (int s = 0; s < 2; ++s) {
                    int grow = t0 - 56 + 16 * (it + 1) + 8 * p01 + 4 * s + g;
                    bool ok = colOK && (grow >= 0) && (grow < T_);
                    xv[s] = ok ? *(const float4*)(xb + (size_t)grow * X_ + gcol) : make_float4(0.f, 0.f, 0.f, 0.f);
                    yv[s] = ok ? *(const float4*)(yb + (size_t)grow * X_ + gcol) : make_float4(0.f, 0.f, 0.f, 0.f);
                }
            }
            barrier_lgkm();
            gbase += 2; if (gbase >= 18) gbase -= 18;
        }
    } else {
        // ===================== consumer loop =====================
        long a_t[4];
#pragma unroll
        for (int c = 0; c < 4; ++c) {
            float vv[8];
#pragma unroll
            for (int sl = 0; sl < 8; ++sl) {
                int idx = 32 * c + 8 * g + sl - ln16 - 6;
                vv[sl] = (idx >= 0 && idx <= 100) ? ktn[idx] * 16.0f : 0.0f;
            }
            int lo = __builtin_amdgcn_cvt_pk_fp8_f32(vv[0], vv[1], 0, false);
            lo     = __builtin_amdgcn_cvt_pk_fp8_f32(vv[2], vv[3], lo, true);
            int hi = __builtin_amdgcn_cvt_pk_fp8_f32(vv[4], vv[5], 0, false);
            hi     = __builtin_amdgcn_cvt_pk_fp8_f32(vv[6], vv[7], hi, true);
            a_t[c] = (long)(((unsigned long long)(unsigned)hi << 32) | (unsigned)lo);
        }

        int gbase = 0;
        for (int it = 0; it <= itmax; ++it) {
            if (it >= 9) {
                const int m = it - 9;
                f32x4 acc[5];
#pragma unroll
                for (int f = 0; f < 5; ++f) { acc[f][0] = 0.f; acc[f][1] = 0.f; acc[f][2] = 0.f; acc[f][3] = 0.f; }
#pragma unroll
                for (int c = 0; c < 4; ++c) {
                    int u = gbase + 4 * c + g; if (u >= 18) u -= 18;   // slot of row-group 2m+4c+g
#pragma unroll
                    for (int f = 0; f < 5; ++f) {
                        long bfrag = (long)XS[u][f][16 * p01 + ln16];
                        acc[f] = __builtin_amdgcn_mfma_f32_16x16x32_fp8_fp8(a_t[c], bfrag, acc[f], 0, 0, 0);
                    }
                }
                const float s_ = 1.0f / 256.0f;   // undo kt(16)*kx(16) scaling
#pragma unroll
                for (int r = 0; r < 4; ++r) {
                    int t = t0 + 16 * m + 4 * g + r;
                    if (t < t_end) {
                        float a0 = acc[0][r], a1 = acc[1][r];
                        float sa0 = a0 * s_, sa1 = a1 * s_;
                        float cov = fmaf(-sa0, a1, acc[4][r]);
                        float vx  = fmaf(-sa0, a0, acc[2][r]);
                        float vy  = fmaf(-sa1, a1, acc[3][r]);
                        local += 1.0f - cov * rsqrtf(fmaf(vx, vy, 6.5536e-5f));
                    }
                }
            }
            barrier_lgkm();
            gbase += 2; if (gbase >= 18) gbase -= 18;
        }
    }

    // ---- block reduction ----
#pragma unroll
    for (int off = 32; off >= 1; off >>= 1) local += __shfl_down(local, off);
    if ((tid & 63) == 0) wred[tid >> 6] = local;
    __syncthreads();
    if (tid == 0)
        partial[wid] = wred[0] + wred[1] + wred[2] + wred[3];
}

__global__ __launch_bounds__(256) void coh_reduce(const float* __restrict__ partial,
                                                  float* __restrict__ out) {
    __shared__ float wred[4];
    const int tid = threadIdx.x;
    float s = 0.0f;
    for (int i = tid; i < NBLK; i += 256) s += partial[i];
#pragma unroll
    for (int off = 32; off >= 1; off >>= 1) s += __shfl_down(s, off);
    if ((tid & 63) == 0) wred[tid >> 6] = s;
    __syncthreads();
    if (tid == 0)
        out[0] = (wred[0] + wred[1] + wred[2] + wred[3]) *
                 (1.0f / ((float)B_ * (float)T_ * (float)X_));
}

extern "C" void kernel_launch(void* const* d_in, const int* in_sizes, int n_in,
                              void* d_out, int out_size, void* d_ws, size_t ws_size,
                              hipStream_t stream) {
    const float* x = (const float*)d_in[0];
    const float* y = (const float*)d_in[1];
    float* out = (float*)d_out;
    float* partial = (float*)d_ws;   // NBLK floats = 4 KB

    coh9<<<dim3(NBLK), 256, 0, stream>>>(x, y, partial);
    coh_reduce<<<1, 256, 0, stream>>>(partial, out);
}